// Round 1
// baseline (784.639 us; speedup 1.0000x reference)
//
#include <hip/hip_runtime.h>
#include <math.h>

#define NB 2
#define NN 256
#define FF 64
#define HH 64
#define NHEADS 4
#define KK 50
#define CC 256

constexpr int BN = NB * NN;          // 512
constexpr int NPAIR = NB * NN * NN;  // 131072

__device__ __forceinline__ float siluf(float v) { return v / (1.f + __expf(-v)); }
__device__ __forceinline__ float sigmoidf_(float v) { return 1.f / (1.f + __expf(-v)); }
__device__ __forceinline__ float tanh_fast(float x) {
    x = fminf(fmaxf(x, -15.f), 15.f);
    float e = __expf(2.f * x);
    return (e - 1.f) / (e + 1.f);
}

// ---------------------------------------------------------------------------
// K1: edge model. One 64-lane wave per pair (i,j); 4 pairs per block.
// Writes he_mtx [B,N,N,64], sem_logit [B,N,N,4], norm_g [B,N,N].
// ---------------------------------------------------------------------------
__global__ __launch_bounds__(256) void k1_edge(
    const float* __restrict__ h, const float* __restrict__ x,
    const float* __restrict__ means, const float* __restrict__ betas,
    const float* __restrict__ W_in, const float* __restrict__ b_in,
    const float* __restrict__ W_o1, const float* __restrict__ b_o1,
    const float* __restrict__ W_o2, const float* __restrict__ b_o2,
    const float* __restrict__ Ws, const float* __restrict__ bs,
    float* __restrict__ he_mtx, float* __restrict__ sem_logit,
    float* __restrict__ norm_g)
{
    __shared__ float hcat[4][2 * FF];
    __shared__ float rbfhk[4][KK];
    __shared__ float s1[4][HH];
    __shared__ float he[4][HH];

    const int tid = threadIdx.x;
    const int s = tid >> 6;
    const int l = tid & 63;
    const int p = blockIdx.x * 4 + s;      // pair id = (b*N+i)*N + j
    const int b = p >> 16;
    const int rem = p & 65535;
    const int i = rem >> 8;
    const int j = rem & 255;

    const float* hb = h + (size_t)b * NN * FF;
    hcat[s][l]      = hb[j * FF + l];   // h_j first
    hcat[s][FF + l] = hb[i * FF + l];   // then h_i

    const float* xb = x + (size_t)b * NN * 3;
    float dx0 = xb[j * 3 + 0] - xb[i * 3 + 0];
    float dx1 = xb[j * 3 + 1] - xb[i * 3 + 1];
    float dx2 = xb[j * 3 + 2] - xb[i * 3 + 2];
    float d2 = dx0 * dx0 + dx1 * dx1 + dx2 * dx2;
    float nrm = sqrtf(fmaxf(d2, 0.f) + 1e-5f);
    __syncthreads();

    // hk = h_cat @ W_in + b_in ; rbfhk = rbf * hk   (K=50 outputs)
    if (l < KK) {
        float acc = b_in[l];
#pragma unroll 8
        for (int k = 0; k < 2 * FF; k++) acc += hcat[s][k] * W_in[k * KK + l];
        float e = __expf(-nrm) - means[l];
        float rb = __expf(-betas[l] * e * e);
        rbfhk[s][l] = rb * acc;
    }
    __syncthreads();

    // first layer: [h_cat(128), rbfhk(50), norm(1)] @ W_o1 + b_o1, silu
    {
        float acc = b_o1[l];
#pragma unroll 8
        for (int k = 0; k < 2 * FF; k++) acc += hcat[s][k] * W_o1[k * HH + l];
#pragma unroll 5
        for (int k = 0; k < KK; k++) acc += rbfhk[s][k] * W_o1[(2 * FF + k) * HH + l];
        acc += nrm * W_o1[(2 * FF + KK) * HH + l];
        s1[s][l] = siluf(acc);
    }
    __syncthreads();

    // second layer: s1 @ W_o2 + b_o2 -> h_e_mtx
    {
        float acc = b_o2[l];
#pragma unroll 8
        for (int k = 0; k < HH; k++) acc += s1[s][k] * W_o2[k * HH + l];
        he[s][l] = acc;
        he_mtx[(size_t)p * HH + l] = acc;
    }
    __syncthreads();

    // semantic attention logits: celu(he @ Ws + bs, alpha=2) - 1e5*eye
    if (l < NHEADS) {
        float acc = bs[l];
#pragma unroll 8
        for (int k = 0; k < HH; k++) acc += he[s][k] * Ws[k * NHEADS + l];
        float cel = acc > 0.f ? acc : 2.f * expm1f(0.5f * acc);
        if (i == j) cel -= 1e5f;
        sem_logit[(size_t)p * NHEADS + l] = cel;
    }
    if (l == 0) norm_g[p] = nrm;
}

// ---------------------------------------------------------------------------
// K2: the three softmaxes over j. One block per (b,i), thread = j.
// ---------------------------------------------------------------------------
__device__ __forceinline__ float4 block_max4(float4 v, float4* buf) {
    int tid = threadIdx.x;
    buf[tid] = v;
    __syncthreads();
    for (int s = 128; s > 0; s >>= 1) {
        if (tid < s) {
            float4 o = buf[tid + s], m = buf[tid];
            m.x = fmaxf(m.x, o.x); m.y = fmaxf(m.y, o.y);
            m.z = fmaxf(m.z, o.z); m.w = fmaxf(m.w, o.w);
            buf[tid] = m;
        }
        __syncthreads();
    }
    float4 r = buf[0];
    __syncthreads();
    return r;
}

__device__ __forceinline__ float4 block_sum4(float4 v, float4* buf) {
    int tid = threadIdx.x;
    buf[tid] = v;
    __syncthreads();
    for (int s = 128; s > 0; s >>= 1) {
        if (tid < s) {
            float4 o = buf[tid + s], m = buf[tid];
            m.x += o.x; m.y += o.y; m.z += o.z; m.w += o.w;
            buf[tid] = m;
        }
        __syncthreads();
    }
    float4 r = buf[0];
    __syncthreads();
    return r;
}

__global__ __launch_bounds__(256) void k2_attn(
    const float* __restrict__ norm_g, const float* __restrict__ sem_logit,
    const float* __restrict__ log_gamma, float* __restrict__ comb_att)
{
    __shared__ float4 buf[256];
    const int bi = blockIdx.x;        // b*N + i
    const int i = bi & 255;
    const int j = threadIdx.x;
    const size_t base = (size_t)bi * NN + j;

    float g0 = __expf(log_gamma[0]);
    float g1 = __expf(log_gamma[1]);
    float g2 = __expf(log_gamma[2]);
    float g3 = __expf(log_gamma[3]);

    float nrm = norm_g[base];
    float pen = (j == i) ? 1e5f : 0.f;
    float nl = -(nrm + pen);
    float4 el = make_float4(nl * g0, nl * g1, nl * g2, nl * g3);
    float4 sl = ((const float4*)sem_logit)[base];

    // euclidean softmax over j
    float4 m = block_max4(el, buf);
    float4 ev = make_float4(__expf(el.x - m.x), __expf(el.y - m.y),
                            __expf(el.z - m.z), __expf(el.w - m.w));
    float4 sum = block_sum4(ev, buf);
    float4 eucl = make_float4(ev.x / sum.x, ev.y / sum.y, ev.z / sum.z, ev.w / sum.w);

    // semantic softmax over j
    m = block_max4(sl, buf);
    float4 sv = make_float4(__expf(sl.x - m.x), __expf(sl.y - m.y),
                            __expf(sl.z - m.z), __expf(sl.w - m.w));
    sum = block_sum4(sv, buf);
    float4 sem = make_float4(sv.x / sum.x, sv.y / sum.y, sv.z / sum.z, sv.w / sum.w);

    // combined softmax over j of eucl*sem
    float4 cl = make_float4(eucl.x * sem.x, eucl.y * sem.y, eucl.z * sem.z, eucl.w * sem.w);
    m = block_max4(cl, buf);
    float4 cv = make_float4(__expf(cl.x - m.x), __expf(cl.y - m.y),
                            __expf(cl.z - m.z), __expf(cl.w - m.w));
    sum = block_sum4(cv, buf);
    float4 ca = make_float4(cv.x / sum.x, cv.y / sum.y, cv.z / sum.z, cv.w / sum.w);

    ((float4*)comb_att)[base] = ca;
}

// ---------------------------------------------------------------------------
// K3: h_e_att build + coeff = tanh(h_e_att @ Wx) + reductions over j.
// One block per (b,i): 256 threads = 4 waves; thread owns 4 Wx columns,
// wave owns 8 j's of a 32-j LDS tile. Outputs h_e, comb_norm, delta_v.
// ---------------------------------------------------------------------------
__global__ __launch_bounds__(256) void k3_spatial(
    const float* __restrict__ he_mtx, const float* __restrict__ comb_att,
    const float* __restrict__ x, const float* __restrict__ norm_g,
    const float* __restrict__ Wx, const float* __restrict__ Wv_mix,
    float* __restrict__ h_e, float* __restrict__ comb_norm,
    float* __restrict__ delta_v)
{
    __shared__ float hea[32][CC];       // 32 KB: h_e_att tile [j][c]
    __shared__ float xd[32][4];
    __shared__ float red_he[4][CC];
    __shared__ float red_cs[4][CC][3];
    __shared__ float red_dv[256][3];

    const int tid = threadIdx.x;
    const int g = tid >> 6;             // wave id -> j subgroup
    const int cc = tid & 63;
    const int cb = cc * 4;              // first owned Wx column
    const int bi = blockIdx.x;
    const int b = bi >> 8;
    const int i = bi & 255;

    const float4* Wx4 = (const float4*)Wx;
    const float wv0 = Wv_mix[cb + 0], wv1 = Wv_mix[cb + 1];
    const float wv2 = Wv_mix[cb + 2], wv3 = Wv_mix[cb + 3];

    float he_s0 = 0.f, he_s1 = 0.f, he_s2 = 0.f, he_s3 = 0.f;
    float cs[4][3] = {{0.f,0.f,0.f},{0.f,0.f,0.f},{0.f,0.f,0.f},{0.f,0.f,0.f}};
    float dv0 = 0.f, dv1 = 0.f, dv2 = 0.f;

    const float* xb = x + (size_t)b * NN * 3;
    const float xi0 = xb[i * 3 + 0], xi1 = xb[i * 3 + 1], xi2 = xb[i * 3 + 2];

    for (int jt = 0; jt < NN; jt += 32) {
        // stage h_e_att tile: hea[jj][c] = he_mtx[j][c>>2] * comb_att[j][c&3]
        for (int jj = 0; jj < 32; jj++) {
            int j = jt + jj;
            float hv = he_mtx[((size_t)bi * NN + j) * HH + (tid >> 2)];
            float av = comb_att[((size_t)bi * NN + j) * 4 + (tid & 3)];
            hea[jj][tid] = hv * av;
        }
        if (tid < 32) {
            int j = jt + tid;
            float nrm = norm_g[(size_t)bi * NN + j];
            float inv = 1.f / (nrm + 1e-5f);
            xd[tid][0] = (xb[j * 3 + 0] - xi0) * inv;
            xd[tid][1] = (xb[j * 3 + 1] - xi1) * inv;
            xd[tid][2] = (xb[j * 3 + 2] - xi2) * inv;
        }
        __syncthreads();

        float acc[8][4];
#pragma unroll
        for (int jj = 0; jj < 8; jj++)
            for (int r = 0; r < 4; r++) acc[jj][r] = 0.f;

        const int jb = g * 8;
#pragma unroll 4
        for (int k = 0; k < CC; k++) {
            float4 w = Wx4[k * 64 + cc];
#pragma unroll
            for (int jj = 0; jj < 8; jj++) {
                float a = hea[jb + jj][k];
                acc[jj][0] += a * w.x; acc[jj][1] += a * w.y;
                acc[jj][2] += a * w.z; acc[jj][3] += a * w.w;
            }
        }

#pragma unroll
        for (int jj = 0; jj < 8; jj++) {
            int jl = jb + jj;
            float c0 = tanh_fast(acc[jj][0]);
            float c1 = tanh_fast(acc[jj][1]);
            float c2 = tanh_fast(acc[jj][2]);
            float c3 = tanh_fast(acc[jj][3]);
            he_s0 += hea[jl][cb + 0]; he_s1 += hea[jl][cb + 1];
            he_s2 += hea[jl][cb + 2]; he_s3 += hea[jl][cb + 3];
            float x0 = xd[jl][0], x1 = xd[jl][1], x2 = xd[jl][2];
            float wsum = c0 * wv0 + c1 * wv1 + c2 * wv2 + c3 * wv3;
            dv0 += x0 * wsum; dv1 += x1 * wsum; dv2 += x2 * wsum;
            cs[0][0] += x0 * c0; cs[0][1] += x1 * c0; cs[0][2] += x2 * c0;
            cs[1][0] += x0 * c1; cs[1][1] += x1 * c1; cs[1][2] += x2 * c1;
            cs[2][0] += x0 * c2; cs[2][1] += x1 * c2; cs[2][2] += x2 * c2;
            cs[3][0] += x0 * c3; cs[3][1] += x1 * c3; cs[3][2] += x2 * c3;
        }
        __syncthreads();   // before next tile overwrites hea
    }

    // cross-wave reductions
    red_he[g][cb + 0] = he_s0; red_he[g][cb + 1] = he_s1;
    red_he[g][cb + 2] = he_s2; red_he[g][cb + 3] = he_s3;
#pragma unroll
    for (int r = 0; r < 4; r++)
        for (int t = 0; t < 3; t++) red_cs[g][cb + r][t] = cs[r][t];
    red_dv[tid][0] = dv0; red_dv[tid][1] = dv1; red_dv[tid][2] = dv2;
    __syncthreads();

    {
        int c = tid;
        float hv = red_he[0][c] + red_he[1][c] + red_he[2][c] + red_he[3][c];
        h_e[(size_t)bi * CC + c] = hv;
        float m0 = 0.f, m1 = 0.f, m2 = 0.f;
#pragma unroll
        for (int gg = 0; gg < 4; gg++) {
            m0 += red_cs[gg][c][0]; m1 += red_cs[gg][c][1]; m2 += red_cs[gg][c][2];
        }
        const float invn = 1.f / (float)NN;
        m0 *= invn; m1 *= invn; m2 *= invn;
        comb_norm[(size_t)bi * CC + c] = m0 * m0 + m1 * m1 + m2 * m2;
    }
    if (tid < 3) {
        float ssum = 0.f;
        for (int t = 0; t < 256; t++) ssum += red_dv[t][tid];
        delta_v[(size_t)bi * 3 + tid] = ssum * (1.f / (float)NN);
    }
}

// ---------------------------------------------------------------------------
// K4: node MLPs + velocity/position update. One block (64 thr) per (b,i).
// ---------------------------------------------------------------------------
__global__ __launch_bounds__(64) void k4_node(
    const float* __restrict__ h, const float* __restrict__ x, const float* __restrict__ v,
    const float* __restrict__ h_e, const float* __restrict__ comb_norm,
    const float* __restrict__ delta_v,
    const float* __restrict__ Wp1, const float* __restrict__ bp1,
    const float* __restrict__ Wp2, const float* __restrict__ bp2,
    const float* __restrict__ Wn1, const float* __restrict__ bn1,
    const float* __restrict__ Wn2, const float* __restrict__ bn2,
    const float* __restrict__ Wvel1, const float* __restrict__ bvel1,
    const float* __restrict__ Wvel2,
    float* __restrict__ out)
{
    __shared__ float cn[CC];
    __shared__ float inb[FF + CC + HH];   // [h, h_e, h_comb]
    __shared__ float tmp[HH];
    __shared__ float hn[HH];

    const int bi = blockIdx.x;
    const int t = threadIdx.x;

#pragma unroll
    for (int r = 0; r < 4; r++) {
        cn[r * 64 + t] = comb_norm[(size_t)bi * CC + r * 64 + t];
        inb[FF + r * 64 + t] = h_e[(size_t)bi * CC + r * 64 + t];
    }
    inb[t] = h[(size_t)bi * FF + t];
    __syncthreads();

    // post_norm_mlp layer 1
    float acc = bp1[t];
#pragma unroll 8
    for (int k = 0; k < CC; k++) acc += cn[k] * Wp1[k * HH + t];
    tmp[t] = siluf(acc);
    __syncthreads();
    // layer 2 -> h_comb
    acc = bp2[t];
#pragma unroll 8
    for (int k = 0; k < HH; k++) acc += tmp[k] * Wp2[k * HH + t];
    inb[FF + CC + t] = siluf(acc);
    __syncthreads();

    // node_mlp
    acc = bn1[t];
#pragma unroll 8
    for (int k = 0; k < FF + CC + HH; k++) acc += inb[k] * Wn1[k * HH + t];
    float n1v = siluf(acc);
    __syncthreads();
    tmp[t] = n1v;
    __syncthreads();
    acc = bn2[t];
#pragma unroll 8
    for (int k = 0; k < HH; k++) acc += tmp[k] * Wn2[k * FF + t];
    float hnew = inb[t] + siluf(acc);
    hn[t] = hnew;
    out[(size_t)bi * FF + t] = hnew;
    __syncthreads();

    // velocity mlp
    acc = bvel1[t];
#pragma unroll 8
    for (int k = 0; k < HH; k++) acc += hn[k] * Wvel1[k * HH + t];
    float val = siluf(acc) * Wvel2[t];
#pragma unroll
    for (int off = 32; off >= 1; off >>= 1) val += __shfl_xor(val, off, 64);
    float vscale = 2.f * sigmoidf_(val);

    if (t < 3) {
        float vv = v[(size_t)bi * 3 + t];
        float vn = delta_v[(size_t)bi * 3 + t] + vscale * vv;
        out[32768 + (size_t)bi * 3 + t] = x[(size_t)bi * 3 + t] + vn;  // x_new
        out[34304 + (size_t)bi * 3 + t] = vn;                           // v_new
    }
}

// ---------------------------------------------------------------------------
extern "C" void kernel_launch(void* const* d_in, const int* in_sizes, int n_in,
                              void* d_out, int out_size, void* d_ws, size_t ws_size,
                              hipStream_t stream)
{
    const float* h        = (const float*)d_in[0];
    const float* x        = (const float*)d_in[1];
    const float* v        = (const float*)d_in[2];
    const float* means    = (const float*)d_in[3];
    const float* betas    = (const float*)d_in[4];
    const float* W_in     = (const float*)d_in[5];
    const float* b_in     = (const float*)d_in[6];
    const float* W_o1     = (const float*)d_in[7];
    const float* b_o1     = (const float*)d_in[8];
    const float* W_o2     = (const float*)d_in[9];
    const float* b_o2     = (const float*)d_in[10];
    const float* Ws       = (const float*)d_in[11];
    const float* bs       = (const float*)d_in[12];
    const float* log_gamma= (const float*)d_in[13];
    const float* Wx       = (const float*)d_in[14];
    const float* Wp1      = (const float*)d_in[15];
    const float* bp1      = (const float*)d_in[16];
    const float* Wp2      = (const float*)d_in[17];
    const float* bp2      = (const float*)d_in[18];
    const float* Wn1      = (const float*)d_in[19];
    const float* bn1      = (const float*)d_in[20];
    const float* Wn2      = (const float*)d_in[21];
    const float* bn2      = (const float*)d_in[22];
    const float* Wv_mix   = (const float*)d_in[23];
    const float* Wvel1    = (const float*)d_in[24];
    const float* bvel1    = (const float*)d_in[25];
    const float* Wvel2    = (const float*)d_in[26];

    float* ws = (float*)d_ws;
    // workspace layout (floats), all offsets 16B-aligned
    float* norm_g    = ws;                 // 131072
    float* he_mtx    = ws + 131072;        // 8388608
    float* sem_logit = ws + 8519680;       // 524288
    float* comb_att  = ws + 9043968;       // 524288
    float* h_e       = ws + 9568256;       // 131072
    float* comb_norm = ws + 9699328;       // 131072
    float* delta_v   = ws + 9830400;       // 1536

    k1_edge<<<dim3(NPAIR / 4), dim3(256), 0, stream>>>(
        h, x, means, betas, W_in, b_in, W_o1, b_o1, W_o2, b_o2, Ws, bs,
        he_mtx, sem_logit, norm_g);

    k2_attn<<<dim3(BN), dim3(256), 0, stream>>>(norm_g, sem_logit, log_gamma, comb_att);

    k3_spatial<<<dim3(BN), dim3(256), 0, stream>>>(
        he_mtx, comb_att, x, norm_g, Wx, Wv_mix, h_e, comb_norm, delta_v);

    k4_node<<<dim3(BN), dim3(64), 0, stream>>>(
        h, x, v, h_e, comb_norm, delta_v,
        Wp1, bp1, Wp2, bp2, Wn1, bn1, Wn2, bn2, Wvel1, bvel1, Wvel2,
        (float*)d_out);
}